// Round 1
// baseline (246.233 us; speedup 1.0000x reference)
//
#include <hip/hip_runtime.h>

#define BATCH 4096
#define D_IN 1024
#define D_OUT 1024
#define N_EXPERTS 8

#define TM 64
#define TN 64
#define TK 32
#define LDP 68   // padded LDS row stride: 68*4=272B = 17*16B -> float4-aligned rows, conflict-light

// ws layout (int32 slots)
#define WS_PERM    0       // [4096] original sample index per sorted position
#define WS_STARTS  4096    // [9] expert segment starts (prefix sums), starts[8]=4096
#define WS_TILE_E  4112    // [71] expert id per m-tile
#define WS_TILE_M  4200    // [71] m0 within expert per m-tile
#define WS_NTILES  4288    // [1] number of m-tiles
#define MAX_TILES  71      // sum ceil(B_e/64) <= 64 + 7

// ---------------------------------------------------------------------------
// Group samples by expert: histogram + prefix + scatter, and build tile list.
// One block, 256 threads. 4096 elements -> a few microseconds.
// ---------------------------------------------------------------------------
__global__ void group_kernel(const int* __restrict__ actions, int* __restrict__ ws) {
    __shared__ int cnt[N_EXPERTS];
    __shared__ int base[N_EXPERTS];
    const int t = threadIdx.x;
    if (t < N_EXPERTS) cnt[t] = 0;
    __syncthreads();
    for (int i = t; i < BATCH; i += 256) atomicAdd(&cnt[actions[i]], 1);
    __syncthreads();
    if (t == 0) {
        int s = 0, nt = 0;
        for (int e = 0; e < N_EXPERTS; ++e) {
            const int c = cnt[e];
            base[e] = s;
            ws[WS_STARTS + e] = s;
            for (int m0 = 0; m0 < c; m0 += TM) {
                ws[WS_TILE_E + nt] = e;
                ws[WS_TILE_M + nt] = m0;
                ++nt;
            }
            s += c;
            cnt[e] = 0;
        }
        ws[WS_STARTS + N_EXPERTS] = s;
        ws[WS_NTILES] = nt;
    }
    __syncthreads();
    for (int i = t; i < BATCH; i += 256) {
        const int a = actions[i];
        const int pos = base[a] + atomicAdd(&cnt[a], 1);
        ws[WS_PERM + pos] = i;
    }
}

// ---------------------------------------------------------------------------
// Per-expert tiled fp32 GEMM over gathered rows.
// Y[r, n] = sum_k X[r, k] * W[e, n, k] + b[e, n], rows r from perm list.
// 64x64 tile / block, 256 threads, 4x4 acc per thread, TK=32 LDS staging.
// ---------------------------------------------------------------------------
__global__ __launch_bounds__(256) void moe_gemm(
    const float* __restrict__ xs, const float* __restrict__ W,
    const float* __restrict__ bias, const int* __restrict__ ws,
    float* __restrict__ out)
{
    const int tix = blockIdx.y;
    if (tix >= ws[WS_NTILES]) return;
    const int e   = ws[WS_TILE_E + tix];
    const int m0  = ws[WS_TILE_M + tix];
    const int s0  = ws[WS_STARTS + e];
    const int cnt = ws[WS_STARTS + e + 1] - s0;
    const int n0  = blockIdx.x * TN;

    __shared__ float Xs[TK][LDP];
    __shared__ float Wt[TK][LDP];
    __shared__ int   rows[TM];

    const int t = threadIdx.x;
    if (t < TM) {
        const int r = m0 + t;
        rows[t] = (r < cnt) ? ws[WS_PERM + s0 + r] : -1;
    }
    __syncthreads();

    const int tx = t & 15;   // n quad: n = n0 + tx*4 + [0..3]
    const int ty = t >> 4;   // m quad: m = ty*4 + [0..3]
    float acc[4][4] = {};

    const float* Wb = W + (size_t)e * (D_OUT * (size_t)D_IN) + (size_t)n0 * D_IN;

    const int lk = t & 7;    // k-quad: k = lk*4 (covers 32 k with float4)
    const int lr = t >> 3;   // row-in-tile 0..31 (two passes cover 64)

    for (int k0 = 0; k0 < D_IN; k0 += TK) {
#pragma unroll
        for (int i = 0; i < 2; ++i) {
            const int rn = i * 32 + lr;
            // X tile (gathered rows)
            const int r = rows[rn];
            float4 v = make_float4(0.f, 0.f, 0.f, 0.f);
            if (r >= 0) v = *(const float4*)(xs + (size_t)r * D_IN + k0 + lk * 4);
            Xs[lk * 4 + 0][rn] = v.x;
            Xs[lk * 4 + 1][rn] = v.y;
            Xs[lk * 4 + 2][rn] = v.z;
            Xs[lk * 4 + 3][rn] = v.w;
            // W tile (contiguous rows of W[e])
            const float4 w = *(const float4*)(Wb + (size_t)rn * D_IN + k0 + lk * 4);
            Wt[lk * 4 + 0][rn] = w.x;
            Wt[lk * 4 + 1][rn] = w.y;
            Wt[lk * 4 + 2][rn] = w.z;
            Wt[lk * 4 + 3][rn] = w.w;
        }
        __syncthreads();
#pragma unroll
        for (int k = 0; k < TK; ++k) {
            const float4 xv = *(const float4*)&Xs[k][ty * 4];
            const float4 wv = *(const float4*)&Wt[k][tx * 4];
            acc[0][0] += xv.x * wv.x; acc[0][1] += xv.x * wv.y; acc[0][2] += xv.x * wv.z; acc[0][3] += xv.x * wv.w;
            acc[1][0] += xv.y * wv.x; acc[1][1] += xv.y * wv.y; acc[1][2] += xv.y * wv.z; acc[1][3] += xv.y * wv.w;
            acc[2][0] += xv.z * wv.x; acc[2][1] += xv.z * wv.y; acc[2][2] += xv.z * wv.z; acc[2][3] += xv.z * wv.w;
            acc[3][0] += xv.w * wv.x; acc[3][1] += xv.w * wv.y; acc[3][2] += xv.w * wv.z; acc[3][3] += xv.w * wv.w;
        }
        __syncthreads();
    }

    const float4 bn = *(const float4*)(bias + e * D_OUT + n0 + tx * 4);
#pragma unroll
    for (int jm = 0; jm < 4; ++jm) {
        const int r = rows[ty * 4 + jm];
        if (r >= 0) {
            float4 o;
            o.x = acc[jm][0] + bn.x;
            o.y = acc[jm][1] + bn.y;
            o.z = acc[jm][2] + bn.z;
            o.w = acc[jm][3] + bn.w;
            *(float4*)(out + (size_t)r * D_OUT + n0 + tx * 4) = o;
        }
    }
}

// ---------------------------------------------------------------------------
// Passthrough tail outputs: mxs then actions, value-converted to float.
// ---------------------------------------------------------------------------
__global__ void meta_float_kernel(const int* __restrict__ mxs,
                                  const int* __restrict__ actions,
                                  float* __restrict__ out) {
    const int i = blockIdx.x * 256 + threadIdx.x;
    if (i < BATCH) {
        out[BATCH * D_OUT + i] = (float)mxs[i];
        out[BATCH * D_OUT + BATCH + i] = (float)actions[i];
    }
}

// Fallback if the harness keeps actions as raw int64 (2 float slots each).
__global__ void meta_raw64_kernel(const int* __restrict__ mxs,
                                  const int* __restrict__ actions,
                                  float* __restrict__ out) {
    const int i = blockIdx.x * 256 + threadIdx.x;
    if (i < BATCH) {
        out[BATCH * D_OUT + i] = (float)mxs[i];
        long long* a64 = (long long*)(out + BATCH * D_OUT + BATCH);
        a64[i] = (long long)actions[i];
    }
}

extern "C" void kernel_launch(void* const* d_in, const int* in_sizes, int n_in,
                              void* d_out, int out_size, void* d_ws, size_t ws_size,
                              hipStream_t stream) {
    const float* xs      = (const float*)d_in[0];
    const int*   mxs     = (const int*)d_in[1];
    const int*   actions = (const int*)d_in[2];
    const float* W       = (const float*)d_in[3];
    const float* bias    = (const float*)d_in[4];
    float* out = (float*)d_out;
    int*   ws  = (int*)d_ws;

    group_kernel<<<1, 256, 0, stream>>>(actions, ws);

    dim3 grid(D_OUT / TN, MAX_TILES, 1);
    moe_gemm<<<grid, 256, 0, stream>>>(xs, W, bias, ws, out);

    const int metaOff = BATCH * D_OUT;
    if (out_size >= metaOff + 3 * BATCH) {
        meta_raw64_kernel<<<(BATCH + 255) / 256, 256, 0, stream>>>(mxs, actions, out);
    } else if (out_size >= metaOff + 2 * BATCH) {
        meta_float_kernel<<<(BATCH + 255) / 256, 256, 0, stream>>>(mxs, actions, out);
    }
}

// Round 2
// 164.096 us; speedup vs baseline: 1.5005x; 1.5005x over previous
//
#include <hip/hip_runtime.h>

#define BATCH 4096
#define D_IN 1024
#define D_OUT 1024
#define N_EXPERTS 8

#define TM 128
#define TN 128
#define TK 32
#define MAX_TILES 39   // sum ceil(c_e/128) <= 32 + 7

// ws layout (int32 slots)
#define WS_PERM    0       // [4096]
#define WS_STARTS  4096    // [9]
#define WS_TILE_E  4112    // [39]
#define WS_TILE_M  4160    // [39]
#define WS_NTILES  4224    // [1]

typedef __attribute__((ext_vector_type(8))) short short8;   // 8 x bf16 (4 VGPRs)
typedef __attribute__((ext_vector_type(4))) float f32x4;

// ---------------------------------------------------------------------------
// Group samples by expert + build 128-row tile list. One block.
// ---------------------------------------------------------------------------
__global__ void group_kernel(const int* __restrict__ actions, int* __restrict__ ws) {
    __shared__ int cnt[N_EXPERTS];
    __shared__ int base[N_EXPERTS];
    const int t = threadIdx.x;
    if (t < N_EXPERTS) cnt[t] = 0;
    __syncthreads();
    for (int i = t; i < BATCH; i += 256) atomicAdd(&cnt[actions[i]], 1);
    __syncthreads();
    if (t == 0) {
        int s = 0, nt = 0;
        for (int e = 0; e < N_EXPERTS; ++e) {
            const int c = cnt[e];
            base[e] = s;
            ws[WS_STARTS + e] = s;
            for (int m0 = 0; m0 < c; m0 += TM) {
                ws[WS_TILE_E + nt] = e;
                ws[WS_TILE_M + nt] = m0;
                ++nt;
            }
            s += c;
            cnt[e] = 0;
        }
        ws[WS_STARTS + N_EXPERTS] = s;
        ws[WS_NTILES] = nt;
    }
    __syncthreads();
    for (int i = t; i < BATCH; i += 256) {
        const int a = actions[i];
        const int pos = base[a] + atomicAdd(&cnt[a], 1);
        ws[WS_PERM + pos] = i;
    }
}

// fp32 -> bf16 hi/lo split (truncation; lo captures next 8 mantissa bits)
__device__ __forceinline__ void cvt8(const float4 a, const float4 b,
                                     short8& h, short8& l) {
    float f[8] = {a.x, a.y, a.z, a.w, b.x, b.y, b.z, b.w};
#pragma unroll
    for (int i = 0; i < 8; ++i) {
        const unsigned u = __float_as_uint(f[i]);
        h[i] = (short)(u >> 16);
        const float r = f[i] - __uint_as_float(u & 0xffff0000u);
        l[i] = (short)(__float_as_uint(r) >> 16);
    }
}

// ---------------------------------------------------------------------------
// Split-bf16 MFMA GEMM over gathered rows.
// Y[r,n] = sum_k X[r,k] * W[e,n,k] + b[e,n]
// 128x128 tile / block, 4 waves each computing a 64x64 quadrant as 4x4 grid
// of 16x16x32 MFMA tiles. LDS holds bf16 hi/lo tiles in fragment-major
// layout (lane*16B contiguous -> conflict-free ds_read_b128 / write_b128).
// ---------------------------------------------------------------------------
__global__ __launch_bounds__(256) void moe_gemm(
    const float* __restrict__ xs, const float* __restrict__ W,
    const float* __restrict__ bias, const int* __restrict__ ws,
    float* __restrict__ out)
{
    const int tix = blockIdx.y;
    if (tix >= ws[WS_NTILES]) return;
    const int e   = ws[WS_TILE_E + tix];
    const int m0  = ws[WS_TILE_M + tix];
    const int s0  = ws[WS_STARTS + e];
    const int cnt = ws[WS_STARTS + e + 1] - s0;
    const int n0  = blockIdx.x * TN;

    __shared__ short Ahi[TM * TK];   // fragment-major: [mi(8)][lane(64)][8]
    __shared__ short Alo[TM * TK];
    __shared__ short Bhi[TN * TK];
    __shared__ short Blo[TN * TK];
    __shared__ int   rows_s[TM];

    const int t = threadIdx.x;
    if (t < TM) {
        const int r = m0 + t;
        rows_s[t] = (r < cnt) ? ws[WS_PERM + s0 + r] : -1;
    }
    __syncthreads();

    const int lane = t & 63;
    const int wave = t >> 6;
    const int wm = (wave & 1) * 64;   // quadrant m base within 128-tile
    const int wn = (wave >> 1) * 64;  // quadrant n base

    const float zf = 0.f;
    f32x4 acc[4][4];
#pragma unroll
    for (int mi = 0; mi < 4; ++mi)
#pragma unroll
        for (int nj = 0; nj < 4; ++nj)
            acc[mi][nj] = (f32x4){zf, zf, zf, zf};

    const float* Wb = W + (size_t)e * (D_OUT * (size_t)D_IN) + (size_t)n0 * D_IN;

    const int j  = t & 3;    // k-chunk (8 floats each)
    const int rr = t >> 2;   // 0..63; rows rr and rr+64

    for (int k0 = 0; k0 < D_IN; k0 += TK) {
        __syncthreads();
#pragma unroll
        for (int i = 0; i < 2; ++i) {
            const int m   = i * 64 + rr;
            const int off = (m >> 4) * 512 + (j * 16 + (m & 15)) * 8;
            // X tile (gathered rows)
            const int r = rows_s[m];
            float4 v0 = make_float4(0.f, 0.f, 0.f, 0.f), v1 = v0;
            if (r >= 0) {
                const float* p = xs + (size_t)r * D_IN + k0 + j * 8;
                v0 = *(const float4*)p;
                v1 = *(const float4*)(p + 4);
            }
            short8 h, l;
            cvt8(v0, v1, h, l);
            *(short8*)&Ahi[off] = h;
            *(short8*)&Alo[off] = l;
            // W tile (contiguous rows of W[e], n = m index here)
            const float* q = Wb + (size_t)m * D_IN + k0 + j * 8;
            const float4 w0 = *(const float4*)q;
            const float4 w1 = *(const float4*)(q + 4);
            cvt8(w0, w1, h, l);
            *(short8*)&Bhi[off] = h;
            *(short8*)&Blo[off] = l;
        }
        __syncthreads();

        short8 ah[4], al[4], bh[4], bl[4];
#pragma unroll
        for (int i2 = 0; i2 < 4; ++i2) {
            const int aoff = ((wm >> 4) + i2) * 512 + lane * 8;
            ah[i2] = *(const short8*)&Ahi[aoff];
            al[i2] = *(const short8*)&Alo[aoff];
            const int boff = ((wn >> 4) + i2) * 512 + lane * 8;
            bh[i2] = *(const short8*)&Bhi[boff];
            bl[i2] = *(const short8*)&Blo[boff];
        }
#pragma unroll
        for (int mi = 0; mi < 4; ++mi)
#pragma unroll
            for (int nj = 0; nj < 4; ++nj) {
                acc[mi][nj] = __builtin_amdgcn_mfma_f32_16x16x32_bf16(ah[mi], bh[nj], acc[mi][nj], 0, 0, 0);
                acc[mi][nj] = __builtin_amdgcn_mfma_f32_16x16x32_bf16(ah[mi], bl[nj], acc[mi][nj], 0, 0, 0);
                acc[mi][nj] = __builtin_amdgcn_mfma_f32_16x16x32_bf16(al[mi], bh[nj], acc[mi][nj], 0, 0, 0);
            }
    }

    // Epilogue: C/D layout col=lane&15, row=(lane>>4)*4+reg
    const int cl = lane & 15;
    const int qd = lane >> 4;
    float bv[4];
#pragma unroll
    for (int nj = 0; nj < 4; ++nj)
        bv[nj] = bias[e * D_OUT + n0 + wn + nj * 16 + cl];
#pragma unroll
    for (int mi = 0; mi < 4; ++mi) {
#pragma unroll
        for (int reg = 0; reg < 4; ++reg) {
            const int mloc = wm + mi * 16 + qd * 4 + reg;
            const int r = rows_s[mloc];
            if (r >= 0) {
                float* orow = out + (size_t)r * D_OUT + n0 + wn + cl;
#pragma unroll
                for (int nj = 0; nj < 4; ++nj)
                    orow[nj * 16] = acc[mi][nj][reg] + bv[nj];
            }
        }
    }
}

// ---------------------------------------------------------------------------
// Passthrough tail outputs (same logic that passed in R0).
// ---------------------------------------------------------------------------
__global__ void meta_float_kernel(const int* __restrict__ mxs,
                                  const int* __restrict__ actions,
                                  float* __restrict__ out) {
    const int i = blockIdx.x * 256 + threadIdx.x;
    if (i < BATCH) {
        out[BATCH * D_OUT + i] = (float)mxs[i];
        out[BATCH * D_OUT + BATCH + i] = (float)actions[i];
    }
}

__global__ void meta_raw64_kernel(const int* __restrict__ mxs,
                                  const int* __restrict__ actions,
                                  float* __restrict__ out) {
    const int i = blockIdx.x * 256 + threadIdx.x;
    if (i < BATCH) {
        out[BATCH * D_OUT + i] = (float)mxs[i];
        long long* a64 = (long long*)(out + BATCH * D_OUT + BATCH);
        a64[i] = (long long)actions[i];
    }
}

extern "C" void kernel_launch(void* const* d_in, const int* in_sizes, int n_in,
                              void* d_out, int out_size, void* d_ws, size_t ws_size,
                              hipStream_t stream) {
    const float* xs      = (const float*)d_in[0];
    const int*   mxs     = (const int*)d_in[1];
    const int*   actions = (const int*)d_in[2];
    const float* W       = (const float*)d_in[3];
    const float* bias    = (const float*)d_in[4];
    float* out = (float*)d_out;
    int*   ws  = (int*)d_ws;

    group_kernel<<<1, 256, 0, stream>>>(actions, ws);

    dim3 grid(D_OUT / TN, MAX_TILES, 1);
    moe_gemm<<<grid, 256, 0, stream>>>(xs, W, bias, ws, out);

    const int metaOff = BATCH * D_OUT;
    if (out_size >= metaOff + 3 * BATCH) {
        meta_raw64_kernel<<<(BATCH + 255) / 256, 256, 0, stream>>>(mxs, actions, out);
    } else if (out_size >= metaOff + 2 * BATCH) {
        meta_float_kernel<<<(BATCH + 255) / 256, 256, 0, stream>>>(mxs, actions, out);
    }
}

// Round 3
// 158.360 us; speedup vs baseline: 1.5549x; 1.0362x over previous
//
#include <hip/hip_runtime.h>

#define BATCH 4096
#define D_IN 1024
#define D_OUT 1024
#define N_EXPERTS 8

#define TM 64
#define TN 128
#define TK 32
#define MAX_TILES 71   // sum ceil(c_e/64) <= 64 + 7

// ws layout (int32 slots)
#define WS_PERM    0       // [4096]
#define WS_STARTS  4096    // [9]
#define WS_TILE_E  4112    // [71]
#define WS_TILE_M  4200    // [71]
#define WS_NTILES  4288    // [1]

typedef __attribute__((ext_vector_type(8))) short short8;   // 8 x bf16 (4 VGPRs)
typedef __attribute__((ext_vector_type(4))) float f32x4;

// ---------------------------------------------------------------------------
// Group samples by expert + build 64-row tile list. One block.
// ---------------------------------------------------------------------------
__global__ void group_kernel(const int* __restrict__ actions, int* __restrict__ ws) {
    __shared__ int cnt[N_EXPERTS];
    __shared__ int base[N_EXPERTS];
    const int t = threadIdx.x;
    if (t < N_EXPERTS) cnt[t] = 0;
    __syncthreads();
    for (int i = t; i < BATCH; i += 256) atomicAdd(&cnt[actions[i]], 1);
    __syncthreads();
    if (t == 0) {
        int s = 0, nt = 0;
        for (int e = 0; e < N_EXPERTS; ++e) {
            const int c = cnt[e];
            base[e] = s;
            ws[WS_STARTS + e] = s;
            for (int m0 = 0; m0 < c; m0 += TM) {
                ws[WS_TILE_E + nt] = e;
                ws[WS_TILE_M + nt] = m0;
                ++nt;
            }
            s += c;
            cnt[e] = 0;
        }
        ws[WS_STARTS + N_EXPERTS] = s;
        ws[WS_NTILES] = nt;
    }
    __syncthreads();
    for (int i = t; i < BATCH; i += 256) {
        const int a = actions[i];
        const int pos = base[a] + atomicAdd(&cnt[a], 1);
        ws[WS_PERM + pos] = i;
    }
}

// fp32 -> bf16 hi/lo split (truncation; lo captures next 8 mantissa bits)
__device__ __forceinline__ void cvt8(const float4 a, const float4 b,
                                     short8& h, short8& l) {
    float f[8] = {a.x, a.y, a.z, a.w, b.x, b.y, b.z, b.w};
#pragma unroll
    for (int i = 0; i < 8; ++i) {
        const unsigned u = __float_as_uint(f[i]);
        h[i] = (short)(u >> 16);
        const float r = f[i] - __uint_as_float(u & 0xffff0000u);
        l[i] = (short)(__float_as_uint(r) >> 16);
    }
}

// ---------------------------------------------------------------------------
// Split-bf16 MFMA GEMM over gathered rows.
// TM=64 x TN=128 tile / block (more blocks -> 2 blocks/CU for overlap).
// 4 waves in a 2x2 grid; each wave computes a 32x64 quadrant as a 2x4 grid
// of 16x16x32 MFMA tiles, 3 MFMA per tile (hi*hi + hi*lo + lo*hi).
// LDS holds bf16 hi/lo tiles in fragment-major layout (lane*16B contiguous).
// ---------------------------------------------------------------------------
__global__ __launch_bounds__(256) void moe_gemm(
    const float* __restrict__ xs, const float* __restrict__ W,
    const float* __restrict__ bias, const int* __restrict__ ws,
    float* __restrict__ out)
{
    const int tix = blockIdx.y;
    if (tix >= ws[WS_NTILES]) return;
    const int e   = ws[WS_TILE_E + tix];
    const int m0  = ws[WS_TILE_M + tix];
    const int s0  = ws[WS_STARTS + e];
    const int cnt = ws[WS_STARTS + e + 1] - s0;
    const int n0  = blockIdx.x * TN;

    __shared__ short Ahi[TM * TK];   // fragment-major: [tile(4)][lane(64)][8]
    __shared__ short Alo[TM * TK];
    __shared__ short Bhi[TN * TK];   // [tile(8)][lane(64)][8]
    __shared__ short Blo[TN * TK];
    __shared__ int   rows_s[TM];

    const int t = threadIdx.x;
    if (t < TM) {
        const int r = m0 + t;
        rows_s[t] = (r < cnt) ? ws[WS_PERM + s0 + r] : -1;
    }
    __syncthreads();

    const int lane = t & 63;
    const int wave = t >> 6;
    const int wm = (wave & 1) * 32;   // quadrant m base (0 or 32)
    const int wn = (wave >> 1) * 64;  // quadrant n base (0 or 64)

    const float zf = 0.f;
    f32x4 acc[2][4];
#pragma unroll
    for (int mi = 0; mi < 2; ++mi)
#pragma unroll
        for (int nj = 0; nj < 4; ++nj)
            acc[mi][nj] = (f32x4){zf, zf, zf, zf};

    const float* Wb = W + (size_t)e * (D_OUT * (size_t)D_IN) + (size_t)n0 * D_IN;

    const int j  = t & 3;    // k-octet: k = j*8 .. j*8+7
    const int rr = t >> 2;   // 0..63

    // Precompute A-row pointer (row may be -1)
    const int arow = rows_s[rr];
    const float* aptr = (arow >= 0) ? (xs + (size_t)arow * D_IN + j * 8) : nullptr;
    const int aoff_st = (rr >> 4) * 512 + (j * 16 + (rr & 15)) * 8;

    for (int k0 = 0; k0 < D_IN; k0 += TK) {
        __syncthreads();
        // --- stage A (64 rows, gathered) ---
        {
            float4 v0 = make_float4(0.f, 0.f, 0.f, 0.f), v1 = v0;
            if (aptr) {
                v0 = *(const float4*)(aptr + k0);
                v1 = *(const float4*)(aptr + k0 + 4);
            }
            short8 h, l;
            cvt8(v0, v1, h, l);
            *(short8*)&Ahi[aoff_st] = h;
            *(short8*)&Alo[aoff_st] = l;
        }
        // --- stage B (128 rows of W[e] slice) ---
#pragma unroll
        for (int i = 0; i < 2; ++i) {
            const int n   = i * 64 + rr;
            const int off = (n >> 4) * 512 + (j * 16 + (n & 15)) * 8;
            const float* q = Wb + (size_t)n * D_IN + k0 + j * 8;
            const float4 w0 = *(const float4*)q;
            const float4 w1 = *(const float4*)(q + 4);
            short8 h, l;
            cvt8(w0, w1, h, l);
            *(short8*)&Bhi[off] = h;
            *(short8*)&Blo[off] = l;
        }
        __syncthreads();

        short8 ah[2], al[2], bh[4], bl[4];
#pragma unroll
        for (int i2 = 0; i2 < 2; ++i2) {
            const int aoff = ((wm >> 4) + i2) * 512 + lane * 8;
            ah[i2] = *(const short8*)&Ahi[aoff];
            al[i2] = *(const short8*)&Alo[aoff];
        }
#pragma unroll
        for (int i2 = 0; i2 < 4; ++i2) {
            const int boff = ((wn >> 4) + i2) * 512 + lane * 8;
            bh[i2] = *(const short8*)&Bhi[boff];
            bl[i2] = *(const short8*)&Blo[boff];
        }
#pragma unroll
        for (int mi = 0; mi < 2; ++mi)
#pragma unroll
            for (int nj = 0; nj < 4; ++nj) {
                acc[mi][nj] = __builtin_amdgcn_mfma_f32_16x16x32_bf16(ah[mi], bh[nj], acc[mi][nj], 0, 0, 0);
                acc[mi][nj] = __builtin_amdgcn_mfma_f32_16x16x32_bf16(ah[mi], bl[nj], acc[mi][nj], 0, 0, 0);
                acc[mi][nj] = __builtin_amdgcn_mfma_f32_16x16x32_bf16(al[mi], bh[nj], acc[mi][nj], 0, 0, 0);
            }
    }

    // Epilogue: C/D layout col=lane&15, row=(lane>>4)*4+reg
    const int cl = lane & 15;
    const int qd = lane >> 4;
    float bv[4];
#pragma unroll
    for (int nj = 0; nj < 4; ++nj)
        bv[nj] = bias[e * D_OUT + n0 + wn + nj * 16 + cl];
#pragma unroll
    for (int mi = 0; mi < 2; ++mi) {
#pragma unroll
        for (int reg = 0; reg < 4; ++reg) {
            const int mloc = wm + mi * 16 + qd * 4 + reg;
            const int r = rows_s[mloc];
            if (r >= 0) {
                float* orow = out + (size_t)r * D_OUT + n0 + wn + cl;
#pragma unroll
                for (int nj = 0; nj < 4; ++nj)
                    orow[nj * 16] = acc[mi][nj][reg] + bv[nj];
            }
        }
    }
}

// ---------------------------------------------------------------------------
// Passthrough tail outputs (unchanged from R0/R1 — validated).
// ---------------------------------------------------------------------------
__global__ void meta_float_kernel(const int* __restrict__ mxs,
                                  const int* __restrict__ actions,
                                  float* __restrict__ out) {
    const int i = blockIdx.x * 256 + threadIdx.x;
    if (i < BATCH) {
        out[BATCH * D_OUT + i] = (float)mxs[i];
        out[BATCH * D_OUT + BATCH + i] = (float)actions[i];
    }
}

__global__ void meta_raw64_kernel(const int* __restrict__ mxs,
                                  const int* __restrict__ actions,
                                  float* __restrict__ out) {
    const int i = blockIdx.x * 256 + threadIdx.x;
    if (i < BATCH) {
        out[BATCH * D_OUT + i] = (float)mxs[i];
        long long* a64 = (long long*)(out + BATCH * D_OUT + BATCH);
        a64[i] = (long long)actions[i];
    }
}

extern "C" void kernel_launch(void* const* d_in, const int* in_sizes, int n_in,
                              void* d_out, int out_size, void* d_ws, size_t ws_size,
                              hipStream_t stream) {
    const float* xs      = (const float*)d_in[0];
    const int*   mxs     = (const int*)d_in[1];
    const int*   actions = (const int*)d_in[2];
    const float* W       = (const float*)d_in[3];
    const float* bias    = (const float*)d_in[4];
    float* out = (float*)d_out;
    int*   ws  = (int*)d_ws;

    group_kernel<<<1, 256, 0, stream>>>(actions, ws);

    dim3 grid(D_OUT / TN, MAX_TILES, 1);
    moe_gemm<<<grid, 256, 0, stream>>>(xs, W, bias, ws, out);

    const int metaOff = BATCH * D_OUT;
    if (out_size >= metaOff + 3 * BATCH) {
        meta_raw64_kernel<<<(BATCH + 255) / 256, 256, 0, stream>>>(mxs, actions, out);
    } else if (out_size >= metaOff + 2 * BATCH) {
        meta_float_kernel<<<(BATCH + 255) / 256, 256, 0, stream>>>(mxs, actions, out);
    }
}